// Round 15
// baseline (95.883 us; speedup 1.0000x reference)
//
#include <hip/hip_runtime.h>

// CRF-RNN mean-field, 2 iterations, N=8192 (32x16x16), C=4.
// TWO kernels total (one per iteration) + two memsets. No split-K, no reduce pass.
// Per-iteration kernel, grid 544:
//  blocks [0,32): spatial (exactly separable Gaussian): h-conv with on-the-fly
//    softmax, then D,W convs in LDS; normalize; (CM*SK)*spN + u -> atomicAdd.
//  blocks [32,544): bilateral N^2: block owns one (h,w) column (16 rows);
//    256 thr = 32 j-lanes x 8 slots x 2 rows; all 8192 j staged in 16 SoA
//    chunks of 512; shfl_xor reduce over j-lanes; normalize; (CM*BK)*blN
//    -> atomicAdd. qnext pre-zeroed; exactly 2 commutative float adds per
//    element => deterministic.

#define HH 32
#define WW 16
#define DDD 16
#define NN (HH * WW * DDD)    // 8192
#define SPB 32                // spatial blocks
#define BILB 512              // bilateral blocks
#define CHK 512               // j per staged chunk
#define NCHK (NN / CHK)       // 16
#define L2E 1.4426950408889634f
#define C18 (L2E / 18.0f)     // spatial: exp(-d^2/18) == exp2(-d^2*C18)
#define SQL2E 1.2011224087864498f   // sqrt(log2 e)
#define SB (SQL2E / 8.0f)     // THETA_ALPHA
#define SC (SQL2E / 0.5f)     // THETA_BETA

#if __has_builtin(__builtin_amdgcn_exp2f)
#define EXP2(x) __builtin_amdgcn_exp2f(x)
#else
#define EXP2(x) exp2f(x)
#endif

__device__ __forceinline__ float bfLO(unsigned int u) {
    return __uint_as_float(u << 16);
}
__device__ __forceinline__ float bfHI(unsigned int u) {
    return __uint_as_float(u & 0xFFFF0000u);
}
__device__ __forceinline__ unsigned int cvtpk(float lo, float hi) {
    unsigned int r;
    asm("v_cvt_pk_bf16_f32 %0, %1, %2" : "=v"(r) : "v"(lo), "v"(hi));
    return r;
}

__global__ __launch_bounds__(256) void iter(
    const float* __restrict__ qcur,  // [N][4] current q (u on iter 1)
    const float* __restrict__ rgb,   // [N][3]
    const float* __restrict__ uin,   // [N][4] unaries
    const float* __restrict__ sk, const float* __restrict__ bk,
    const float* __restrict__ cm,
    float* __restrict__ qnext)       // [N][4], pre-zeroed; atomicAdd target
{
    __shared__ float lds[4608];      // bilat SoA 18KB / spatial A|B 8KB
    int tid = threadIdx.x;

    if (blockIdx.x >= SPB) {
        // ---------------- bilateral N^2 ----------------
        int b = blockIdx.x - SPB;            // 0..511
        int h = b >> 4, w = b & 15;
        int ibase = b << 4;                  // 16 consecutive i: same (h,w)
        int slot = tid >> 5, jlane = tid & 31;
        int i0 = ibase + slot;               // d = slot
        int i1 = ibase + slot + 8;           // d = slot+8

        float fh = (float)(h + 1) * SB;
        float fw = (float)(w + 1) * SB;
        float fd0 = (float)(slot + 1) * SB;
        float fd1 = (float)(slot + 9) * SB;
        float c00 = rgb[3 * i0] * SC, c01 = rgb[3 * i0 + 1] * SC, c02 = rgb[3 * i0 + 2] * SC;
        float c10 = rgb[3 * i1] * SC, c11 = rgb[3 * i1 + 1] * SC, c12 = rgb[3 * i1 + 2] * SC;
        float hw2 = fh * fh + fw * fw;
        float nn0 = -0.5f * (hw2 + fd0 * fd0 + c00 * c00 + c01 * c01 + c02 * c02);
        float nn1 = -0.5f * (hw2 + fd1 * fd1 + c10 * c10 + c11 * c11 + c12 * c12);

        float2* gHW = (float2*)lds;              // [512] {gh,gw}
        float2* gDN = (float2*)(lds + 1024);     // [512] {gd,nj}
        float2* C01 = (float2*)(lds + 2048);     // [512] {c0,c1}
        float*  C2a = lds + 3072;                // [512] c2
        uint2*  SMa = (uint2*)(lds + 3584);      // [512] bf16x4 sm

        float a0 = 0, a1 = 0, a2 = 0, a3 = 0;   // row i0
        float b0 = 0, b1 = 0, b2 = 0, b3 = 0;   // row i1

        for (int c = 0; c < NCHK; ++c) {
            __syncthreads();                 // prev chunk fully consumed
            #pragma unroll
            for (int tt = 0; tt < 2; ++tt) {
                int t = tid + tt * 256;
                int j = c * CHK + t;
                int jh = j >> 8, jr = j & 255, jw = jr >> 4, jd = jr & 15;
                float gh = (float)(jh + 1) * SB;
                float gw = (float)(jw + 1) * SB;
                float gd = (float)(jd + 1) * SB;
                float e0c = rgb[3 * j] * SC, e1c = rgb[3 * j + 1] * SC, e2c = rgb[3 * j + 2] * SC;
                float nj = -0.5f * (gh * gh + gw * gw + gd * gd +
                                    e0c * e0c + e1c * e1c + e2c * e2c);
                float4 q = ((const float4*)qcur)[j];
                float m = fmaxf(fmaxf(q.x, q.y), fmaxf(q.z, q.w));
                float s0 = EXP2((q.x - m) * L2E), s1 = EXP2((q.y - m) * L2E);
                float s2 = EXP2((q.z - m) * L2E), s3 = EXP2((q.w - m) * L2E);
                float rs = 1.0f / (s0 + s1 + s2 + s3);
                gHW[t] = make_float2(gh, gw);
                gDN[t] = make_float2(gd, nj);
                C01[t] = make_float2(e0c, e1c);
                C2a[t] = e2c;
                SMa[t] = make_uint2(cvtpk(s0 * rs, s1 * rs), cvtpk(s2 * rs, s3 * rs));
            }
            __syncthreads();

            #pragma unroll 4
            for (int k = 0; k < CHK / 32; ++k) {
                int jl = k * 32 + jlane;
                float2 gg = gHW[jl];
                float2 dn = gDN[jl];
                float2 cc = C01[jl];
                float c2v = C2a[jl];
                uint2 sp = SMa[jl];
                float s0 = bfLO(sp.x), s1 = bfHI(sp.x);
                float s2 = bfLO(sp.y), s3 = bfHI(sp.y);
                float bse = fmaf(fh, gg.x, fmaf(fw, gg.y, dn.y));
                float g0 = fmaf(fd0, dn.x, bse + nn0);
                g0 = fmaf(c00, cc.x, g0);
                g0 = fmaf(c01, cc.y, g0);
                g0 = fmaf(c02, c2v, g0);
                float g1 = fmaf(fd1, dn.x, bse + nn1);
                g1 = fmaf(c10, cc.x, g1);
                g1 = fmaf(c11, cc.y, g1);
                g1 = fmaf(c12, c2v, g1);
                float w0 = EXP2(g0);
                float w1 = EXP2(g1);
                a0 = fmaf(w0, s0, a0); a1 = fmaf(w0, s1, a1);
                a2 = fmaf(w0, s2, a2); a3 = fmaf(w0, s3, a3);
                b0 = fmaf(w1, s0, b0); b1 = fmaf(w1, s1, b1);
                b2 = fmaf(w1, s2, b2); b3 = fmaf(w1, s3, b3);
            }
        }

        // reduce over 32 j-lanes (each 32-lane half is one slot)
        #pragma unroll
        for (int m = 16; m >= 1; m >>= 1) {
            a0 += __shfl_xor(a0, m); a1 += __shfl_xor(a1, m);
            a2 += __shfl_xor(a2, m); a3 += __shfl_xor(a3, m);
            b0 += __shfl_xor(b0, m); b1 += __shfl_xor(b1, m);
            b2 += __shfl_xor(b2, m); b3 += __shfl_xor(b3, m);
        }

        if (jlane == 0) {
            float Mb[4][4];
            #pragma unroll
            for (int cR = 0; cR < 4; ++cR)
                #pragma unroll
                for (int e = 0; e < 4; ++e) {
                    float acc = 0.0f;
                    #pragma unroll
                    for (int d = 0; d < 4; ++d)
                        acc += cm[cR * 4 + d] * bk[d * 4 + e];
                    Mb[cR][e] = acc;
                }
            float ra = 1.0f / (a0 + a1 + a2 + a3);
            float na[4] = { a0 * ra, a1 * ra, a2 * ra, a3 * ra };
            float rb = 1.0f / (b0 + b1 + b2 + b3);
            float nb[4] = { b0 * rb, b1 * rb, b2 * rb, b3 * rb };
            #pragma unroll
            for (int cR = 0; cR < 4; ++cR) {
                float va = Mb[cR][0] * na[0] + Mb[cR][1] * na[1] +
                           Mb[cR][2] * na[2] + Mb[cR][3] * na[3];
                float vb = Mb[cR][0] * nb[0] + Mb[cR][1] * nb[1] +
                           Mb[cR][2] * nb[2] + Mb[cR][3] * nb[3];
                atomicAdd(&qnext[4 * i0 + cR], va);
                atomicAdd(&qnext[4 * i1 + cR], vb);
            }
        }
    } else {
        // ---------------- spatial: h-conv (on-the-fly softmax) + D,W convs ----
        int h = blockIdx.x;
        int s = tid;                 // s = w*16 + d
        int w = s >> 4, d = s & 15;

        float h0 = 0, h1 = 0, h2 = 0, h3 = 0;
        for (int hp = 0; hp < HH; ++hp) {
            float4 q = ((const float4*)qcur)[hp * 256 + s];
            float m = fmaxf(fmaxf(q.x, q.y), fmaxf(q.z, q.w));
            float s0 = EXP2((q.x - m) * L2E), s1 = EXP2((q.y - m) * L2E);
            float s2 = EXP2((q.z - m) * L2E), s3 = EXP2((q.w - m) * L2E);
            float rs = 1.0f / (s0 + s1 + s2 + s3);
            float dh = (float)(h - hp);
            float kh = EXP2(-dh * dh * C18) * rs;
            h0 = fmaf(kh, s0, h0); h1 = fmaf(kh, s1, h1);
            h2 = fmaf(kh, s2, h2); h3 = fmaf(kh, s3, h3);
        }
        float* A = lds;              // [256][4]
        float* B = lds + 1024;       // [256][4]
        *((float4*)(A + 4 * s)) = make_float4(h0, h1, h2, h3);
        __syncthreads();

        float t0 = 0, t1 = 0, t2 = 0, t3 = 0;
        #pragma unroll
        for (int dp = 0; dp < DDD; ++dp) {
            float dd = (float)(d - dp);
            float k = EXP2(-dd * dd * C18);
            const float4 v = *((const float4*)(A + 4 * (w * 16 + dp)));
            t0 = fmaf(k, v.x, t0); t1 = fmaf(k, v.y, t1);
            t2 = fmaf(k, v.z, t2); t3 = fmaf(k, v.w, t3);
        }
        *((float4*)(B + 4 * s)) = make_float4(t0, t1, t2, t3);
        __syncthreads();

        float u0 = 0, u1 = 0, u2 = 0, u3 = 0;
        #pragma unroll
        for (int wp = 0; wp < WW; ++wp) {
            float dw = (float)(w - wp);
            float k = EXP2(-dw * dw * C18);
            const float4 v = *((const float4*)(B + 4 * (wp * 16 + d)));
            u0 = fmaf(k, v.x, u0); u1 = fmaf(k, v.y, u1);
            u2 = fmaf(k, v.z, u2); u3 = fmaf(k, v.w, u3);
        }

        float Ms[4][4];
        #pragma unroll
        for (int cR = 0; cR < 4; ++cR)
            #pragma unroll
            for (int e = 0; e < 4; ++e) {
                float acc = 0.0f;
                #pragma unroll
                for (int dd2 = 0; dd2 < 4; ++dd2)
                    acc += cm[cR * 4 + dd2] * sk[dd2 * 4 + e];
                Ms[cR][e] = acc;
            }
        float rs = 1.0f / (u0 + u1 + u2 + u3);
        float ns[4] = { u0 * rs, u1 * rs, u2 * rs, u3 * rs };
        int ig = h * 256 + s;
        #pragma unroll
        for (int cR = 0; cR < 4; ++cR) {
            float v = Ms[cR][0] * ns[0] + Ms[cR][1] * ns[1] +
                      Ms[cR][2] * ns[2] + Ms[cR][3] * ns[3];
            atomicAdd(&qnext[4 * ig + cR], uin[4 * ig + cR] + v);
        }
    }
}

extern "C" void kernel_launch(void* const* d_in, const int* in_sizes, int n_in,
                              void* d_out, int out_size, void* d_ws, size_t ws_size,
                              hipStream_t stream)
{
    const float* u   = (const float*)d_in[0];
    const float* rgb = (const float*)d_in[1];
    const float* sk  = (const float*)d_in[2];
    const float* bk  = (const float*)d_in[3];
    const float* cm  = (const float*)d_in[4];
    float* out = (float*)d_out;

    float* q1 = (float*)d_ws;        // [N][4]

    hipMemsetAsync(q1, 0, (size_t)NN * 4 * sizeof(float), stream);
    hipMemsetAsync(out, 0, (size_t)NN * 4 * sizeof(float), stream);

    dim3 blk(256);
    dim3 grd(SPB + BILB);            // 544

    iter<<<grd, blk, 0, stream>>>(u, rgb, u, sk, bk, cm, q1);
    iter<<<grd, blk, 0, stream>>>(q1, rgb, u, sk, bk, cm, out);
}